// Round 7
// baseline (431.707 us; speedup 1.0000x reference)
//
#include <hip/hip_runtime.h>

// CausalSelfAttention B=4, N=2048, D=1024, scale 1/32.
// f16 convert(+zero l) -> fused QKV GEMM (128x128, BK=64, LDS 2-barrier) ->
// S=QK^T "stream" kernel: NO LDS / NO barriers — A and B MFMA fragments are
// 16B-contiguous along k in global layout, loaded straight into VGPRs.
// Fused mask+exp epilogue + atomic row sums. -> PV stream kernel (same
// structure, causal K-limit, heavy-first), scaled by 1/rowsum.
//
// R6 post-mortem: barrier'd K-loops cost ~5000 cyc/iter vs ~350 compute at
// ~2 blocks/CU (m97-structure wall). Stream kernels remove the barrier
// entirely and run 16-18 independent waves/CU.

typedef __attribute__((ext_vector_type(8))) _Float16 half8;
typedef __attribute__((ext_vector_type(4))) _Float16 half4v;
typedef __attribute__((ext_vector_type(4))) float floatx4;

#define AS1 __attribute__((address_space(1)))
#define AS3 __attribute__((address_space(3)))

__device__ __forceinline__ void load16_lds(void* lds, const void* g) {
  __builtin_amdgcn_global_load_lds((AS1 void*)g, (AS3 void*)lds, 16, 0, 0);
}

// ---------------------------------------------------------------- conv + zero

__global__ __launch_bounds__(256)
void conv_f32_f16(const float* __restrict__ in, _Float16* __restrict__ out,
                  float* __restrict__ l) {
  if (blockIdx.x < 8192) {
    const int i = (blockIdx.x * 256 + threadIdx.x) << 2;
    float4 v = *(const float4*)(in + i);
    half4v o = { (_Float16)v.x, (_Float16)v.y, (_Float16)v.z, (_Float16)v.w };
    *(half4v*)(out + i) = o;
  } else {
    const int i = ((blockIdx.x - 8192) * 256 + threadIdx.x) << 2;
    *(float4*)(l + i) = float4{0.f, 0.f, 0.f, 0.f};
  }
}

// W [1024(k),1024(n)] fp32 -> Wt [n][k] f16 for 3 weights -> [3072][1024]
__global__ __launch_bounds__(256)
void transpose_w(const float* __restrict__ W0, const float* __restrict__ W1,
                 const float* __restrict__ W2, _Float16* __restrict__ Wt) {
  const float* W = blockIdx.z == 0 ? W0 : (blockIdx.z == 1 ? W1 : W2);
  _Float16* out = Wt + (long long)blockIdx.z * 1048576;
  __shared__ _Float16 t[32][33];
  const int tx = threadIdx.x, ty = threadIdx.y;
  const int n0 = blockIdx.x << 5, k0 = blockIdx.y << 5;
#pragma unroll
  for (int i = 0; i < 4; ++i)
    t[ty + i * 8][tx] = (_Float16)W[(long long)(k0 + ty + i * 8) * 1024 + n0 + tx];
  __syncthreads();
#pragma unroll
  for (int i = 0; i < 4; ++i)
    out[(long long)(n0 + ty + i * 8) * 1024 + k0 + tx] = t[tx][ty + i * 8];
}

// ---------------------------------------------------------------- QKV GEMM
// Unchanged (736 TF, conflicts 0): 128x128 tile, BK=64, 4 waves 2x2.
__global__ __launch_bounds__(256)
void gemm_qkv(const _Float16* __restrict__ A, const _Float16* __restrict__ B,
              _Float16* __restrict__ Q, _Float16* __restrict__ Kh,
              _Float16* __restrict__ Vt) {
  const int bm = blockIdx.y, bn = blockIdx.x;
  const _Float16* Ab = A + (long long)bm * 128 * 1024;
  const _Float16* Bb = B + (long long)bn * 128 * 1024;

  __shared__ _Float16 As[128][64];
  __shared__ _Float16 Bs[128][64];

  const int tid = threadIdx.x;
  const int wave = tid >> 6, lane = tid & 63;
  const int quad = lane >> 4, lr = lane & 15;
  const int wm = (wave >> 1) << 6, wn = (wave & 1) << 6;
  const int srow = lane >> 3;
  const int goff = ((lane & 7) ^ srow) << 3;

  floatx4 acc[4][4] = {};
  const _Float16* ga = Ab + (long long)(wave * 8 + srow) * 1024 + goff;
  const _Float16* gb = Bb + (long long)(wave * 8 + srow) * 1024 + goff;

  for (int k0 = 0; k0 < 1024; k0 += 64) {
    __syncthreads();
#pragma unroll
    for (int c = 0; c < 4; ++c) {
      load16_lds(&As[wave * 8 + 32 * c][0], ga + c * 32 * 1024);
      load16_lds(&Bs[wave * 8 + 32 * c][0], gb + c * 32 * 1024);
    }
    ga += 64; gb += 64;
    __syncthreads();

#pragma unroll
    for (int kk = 0; kk < 2; ++kk) {
      half8 af[4], bf[4];
#pragma unroll
      for (int i = 0; i < 4; ++i) {
        const int ra = wm + (i << 4) + lr;
        const int rb = wn + (i << 4) + lr;
        af[i] = *(const half8*)&As[ra][(((kk << 2) + quad) ^ (ra & 7)) << 3];
        bf[i] = *(const half8*)&Bs[rb][(((kk << 2) + quad) ^ (rb & 7)) << 3];
      }
#pragma unroll
      for (int i = 0; i < 4; ++i)
#pragma unroll
        for (int j = 0; j < 4; ++j)
          acc[i][j] = __builtin_amdgcn_mfma_f32_16x16x32_f16(af[i], bf[j], acc[i][j], 0, 0, 0);
    }
  }

  const int colb = bn * 128 + wn + lr;
  const int rowb = bm * 128 + wm + (quad << 2);

  if (bn < 16) {
    _Float16* C = (bn < 8) ? Q : Kh;
    const int cb = colb & 1023;
#pragma unroll
    for (int i = 0; i < 4; ++i)
#pragma unroll
      for (int j = 0; j < 4; ++j)
#pragma unroll
        for (int r = 0; r < 4; ++r)
          C[(long long)(rowb + (i << 4) + r) * 1024 + cb + (j << 4)] =
              (_Float16)acc[i][j][r];
  } else {
    const int b = rowb >> 11;
    const int tb = rowb & 2047;
#pragma unroll
    for (int i = 0; i < 4; ++i) {
      const int tok = tb + (i << 4);
#pragma unroll
      for (int j = 0; j < 4; ++j) {
        const int d = (colb & 1023) + (j << 4);
        half4v v = { (_Float16)acc[i][j][0], (_Float16)acc[i][j][1],
                     (_Float16)acc[i][j][2], (_Float16)acc[i][j][3] };
        *(half4v*)&Vt[(long long)b * 2097152 + (long long)d * 2048 + tok] = v;
      }
    }
  }
}

// ---------------------------------------------------------------- S stream
// Block = 32 q-rows x 256 k-cols; 4 waves, each 32x64 (acc 2x4). No LDS, no
// barriers: A-frag = Q[q][k..k+8], B-frag = K[n][k..k+8] loaded direct from
// global (16B, line-coalesced: 4 quads of one row tile one 64B line).
// Triangular grid, slab-major (bm fast) for K-slab L2 reuse.
// Epilogue: p = exp(mask(s/32)), f16 store, atomic row sums.
__global__ __launch_bounds__(256)
void s_exp_stream(const _Float16* __restrict__ Q, const _Float16* __restrict__ Kh,
                  _Float16* __restrict__ P, float* __restrict__ l) {
  int t = blockIdx.x;
  int s = 0;
  for (;;) { const int c = 64 - 8 * s; if (t < c) break; t -= c; ++s; }
  const int bm = 8 * s + t;            // q-tile index (32 rows), bm >= 8s
  const int bz = blockIdx.y;

  const _Float16* Qb = Q  + (long long)bz * 2097152 + (long long)bm * 32 * 1024;
  const _Float16* Kb = Kh + (long long)bz * 2097152 + (long long)s * 256 * 1024;

  const int tid = threadIdx.x;
  const int wave = tid >> 6, lane = tid & 63;
  const int quad = lane >> 4, lr = lane & 15;

  const _Float16* ap = Qb + (long long)lr * 1024 + (quad << 3);
  const _Float16* bp = Kb + (long long)(wave * 64 + lr) * 1024 + (quad << 3);

  floatx4 acc[2][4] = {};
#pragma unroll 2
  for (int k0 = 0; k0 < 1024; k0 += 32) {
    half8 af[2], bf[4];
    af[0] = *(const half8*)(ap + k0);
    af[1] = *(const half8*)(ap + 16 * 1024 + k0);
#pragma unroll
    for (int j = 0; j < 4; ++j)
      bf[j] = *(const half8*)(bp + j * 16 * 1024 + k0);
#pragma unroll
    for (int i = 0; i < 2; ++i)
#pragma unroll
      for (int j = 0; j < 4; ++j)
        acc[i][j] = __builtin_amdgcn_mfma_f32_16x16x32_f16(af[i], bf[j], acc[i][j], 0, 0, 0);
  }

  const int n0 = s * 256 + wave * 64;
  const int q0 = bm * 32;
  _Float16* Pb = P + (long long)bz * 4194304;
  const float scl = 0.03125f;

  float rs[2][4];
#pragma unroll
  for (int i = 0; i < 2; ++i)
#pragma unroll
    for (int r = 0; r < 4; ++r) rs[i][r] = 0.f;

#pragma unroll
  for (int i = 0; i < 2; ++i)
#pragma unroll
    for (int j = 0; j < 4; ++j)
#pragma unroll
      for (int r = 0; r < 4; ++r) {
        const int q = q0 + (i << 4) + (quad << 2) + r;
        const int kcol = n0 + (j << 4) + lr;
        const float p = (kcol <= q) ? __expf(acc[i][j][r] * scl) : 0.f;
        Pb[(long long)q * 2048 + kcol] = (_Float16)p;
        rs[i][r] += p;
      }

#pragma unroll
  for (int i = 0; i < 2; ++i)
#pragma unroll
    for (int r = 0; r < 4; ++r) {
#pragma unroll
      for (int off = 1; off < 16; off <<= 1)
        rs[i][r] += __shfl_xor(rs[i][r], off);
    }
  if (lr == 0) {
    float* lb = l + bz * 2048;
#pragma unroll
    for (int i = 0; i < 2; ++i)
#pragma unroll
      for (int r = 0; r < 4; ++r)
        atomicAdd(&lb[q0 + (i << 4) + (quad << 2) + r], rs[i][r]);
  }
}

// ---------------------------------------------------------------- PV stream
// Block = 32 q-rows x 256 d-cols; 4 waves, each 32x64. No LDS/barriers:
// A-frag = P[q][k..k+8], B-frag = Vt[d][k..k+8] direct from global.
// k limited causally to bm*32+32; heavy tiles first; d fast for P L2 reuse.
__global__ __launch_bounds__(256)
void pv_stream(const _Float16* __restrict__ P, const _Float16* __restrict__ Vt,
               const float* __restrict__ l, float* __restrict__ out) {
  const int dn = blockIdx.x;           // 0..3
  const int bm = 63 - blockIdx.y;      // heavy (large k) first
  const int bz = blockIdx.z;
  const int kmax = bm * 32 + 32;

  const _Float16* Pb = P  + (long long)bz * 4194304 + (long long)bm * 32 * 2048;
  const _Float16* Vb = Vt + (long long)bz * 2097152 + (long long)dn * 256 * 2048;

  const int tid = threadIdx.x;
  const int wave = tid >> 6, lane = tid & 63;
  const int quad = lane >> 4, lr = lane & 15;

  const _Float16* ap = Pb + (long long)lr * 2048 + (quad << 3);
  const _Float16* bp = Vb + (long long)(wave * 64 + lr) * 2048 + (quad << 3);

  floatx4 acc[2][4] = {};
#pragma unroll 2
  for (int k0 = 0; k0 < kmax; k0 += 32) {
    half8 af[2], bf[4];
    af[0] = *(const half8*)(ap + k0);
    af[1] = *(const half8*)(ap + 16 * 2048 + k0);
#pragma unroll
    for (int j = 0; j < 4; ++j)
      bf[j] = *(const half8*)(bp + j * 16 * 2048 + k0);
#pragma unroll
    for (int i = 0; i < 2; ++i)
#pragma unroll
      for (int j = 0; j < 4; ++j)
        acc[i][j] = __builtin_amdgcn_mfma_f32_16x16x32_f16(af[i], bf[j], acc[i][j], 0, 0, 0);
  }

  const int d0 = dn * 256 + wave * 64;
  const int q0 = bm * 32;
  const float* lb = l + bz * 2048;
  float* Cb = out + (long long)bz * 2097152;

  float linv[2][4];
#pragma unroll
  for (int i = 0; i < 2; ++i)
#pragma unroll
    for (int r = 0; r < 4; ++r)
      linv[i][r] = 1.0f / lb[q0 + (i << 4) + (quad << 2) + r];

#pragma unroll
  for (int i = 0; i < 2; ++i)
#pragma unroll
    for (int j = 0; j < 4; ++j)
#pragma unroll
      for (int r = 0; r < 4; ++r)
        Cb[(long long)(q0 + (i << 4) + (quad << 2) + r) * 1024 + d0 + (j << 4) + lr] =
            acc[i][j][r] * linv[i][r];
}

// ---------------------------------------------------------------- launch

extern "C" void kernel_launch(void* const* d_in, const int* in_sizes, int n_in,
                              void* d_out, int out_size, void* d_ws, size_t ws_size,
                              hipStream_t stream) {
  const float* x  = (const float*)d_in[0];
  const float* Wq = (const float*)d_in[1];
  const float* Wk = (const float*)d_in[2];
  const float* Wv = (const float*)d_in[3];
  float* out = (float*)d_out;

  char* ws = (char*)d_ws;
  _Float16* xh = (_Float16*)(ws);               // 8192x1024 f16   (16 MiB)
  _Float16* Wt = (_Float16*)(ws + 16777216);    // 3072x1024 f16   ( 6 MiB)
  _Float16* Q  = (_Float16*)(ws + 23068672);    // 8192x1024 f16
  _Float16* Kh = (_Float16*)(ws + 39845888);    // 8192x1024 f16
  _Float16* Vt = (_Float16*)(ws + 56623104);    // 4x1024x2048 f16
  _Float16* P  = (_Float16*)(ws + 73400320);    // 4x2048x2048 f16 unnormalized
  float*    l  = (float*)   (ws + 106954752);   // 4x2048 fp32 row sums

  conv_f32_f16<<<8200, 256, 0, stream>>>(x, xh, l);
  transpose_w<<<dim3(32, 32, 3), dim3(32, 8), 0, stream>>>(Wq, Wk, Wv, Wt);

  // fused QKV: [8192,1024] x [3072,1024]^T
  gemm_qkv<<<dim3(24, 64), 256, 0, stream>>>(xh, Wt, Q, Kh, Vt);

  // P_unnorm = exp(mask(Q K^T / 32)) + row sums; slab-major triangular grid
  s_exp_stream<<<dim3(288, 4), 256, 0, stream>>>(Q, Kh, P, l);

  // out = (P V) / l
  pv_stream<<<dim3(4, 64, 4), 256, 0, stream>>>(P, Vt, l, out);
}

// Round 8
// 253.337 us; speedup vs baseline: 1.7041x; 1.7041x over previous
//
#include <hip/hip_runtime.h>

// CausalSelfAttention B=4, N=2048, D=1024, scale 1/32.
// f16 convert(+zero l) -> fused QKV GEMM (128x128, BK=64, 2-barrier) ->
// S=QK^T 64x256 (fused mask+exp + atomic row sums) -> PV 64x256 (causal
// K-limit) / rowsum.  R8: XCD-PINNED grids for S and PV — block b runs on
// XCD b%8 (round-robin dispatch); K/V slabs (256 rows = 512 KB) are assigned
// per-XCD so staging hits the local 4 MB L2 instead of HBM, shrinking the
// per-iteration vmcnt(0) barrier drain (R5 counters: MfmaUtil 8.9%, all-idle
// latency signature). Triangular imbalance balanced by pairing slab bn with
// slab 7-bn (36 blocks per pair).

typedef __attribute__((ext_vector_type(8))) _Float16 half8;
typedef __attribute__((ext_vector_type(4))) _Float16 half4v;
typedef __attribute__((ext_vector_type(4))) float floatx4;

#define AS1 __attribute__((address_space(1)))
#define AS3 __attribute__((address_space(3)))

__device__ __forceinline__ void load16_lds(void* lds, const void* g) {
  __builtin_amdgcn_global_load_lds((AS1 void*)g, (AS3 void*)lds, 16, 0, 0);
}

// ---------------------------------------------------------------- conv + zero

__global__ __launch_bounds__(256)
void conv_f32_f16(const float* __restrict__ in, _Float16* __restrict__ out,
                  float* __restrict__ l) {
  if (blockIdx.x < 8192) {
    const int i = (blockIdx.x * 256 + threadIdx.x) << 2;
    float4 v = *(const float4*)(in + i);
    half4v o = { (_Float16)v.x, (_Float16)v.y, (_Float16)v.z, (_Float16)v.w };
    *(half4v*)(out + i) = o;
  } else {
    const int i = ((blockIdx.x - 8192) * 256 + threadIdx.x) << 2;
    *(float4*)(l + i) = float4{0.f, 0.f, 0.f, 0.f};
  }
}

// W [1024(k),1024(n)] fp32 -> Wt [n][k] f16 for 3 weights -> [3072][1024]
__global__ __launch_bounds__(256)
void transpose_w(const float* __restrict__ W0, const float* __restrict__ W1,
                 const float* __restrict__ W2, _Float16* __restrict__ Wt) {
  const float* W = blockIdx.z == 0 ? W0 : (blockIdx.z == 1 ? W1 : W2);
  _Float16* out = Wt + (long long)blockIdx.z * 1048576;
  __shared__ _Float16 t[32][33];
  const int tx = threadIdx.x, ty = threadIdx.y;
  const int n0 = blockIdx.x << 5, k0 = blockIdx.y << 5;
#pragma unroll
  for (int i = 0; i < 4; ++i)
    t[ty + i * 8][tx] = (_Float16)W[(long long)(k0 + ty + i * 8) * 1024 + n0 + tx];
  __syncthreads();
#pragma unroll
  for (int i = 0; i < 4; ++i)
    out[(long long)(n0 + ty + i * 8) * 1024 + k0 + tx] = t[tx][ty + i * 8];
}

// ---------------------------------------------------------------- QKV GEMM
// Unchanged (736 TF, conflicts 0): 128x128 tile, BK=64, 4 waves 2x2.
__global__ __launch_bounds__(256)
void gemm_qkv(const _Float16* __restrict__ A, const _Float16* __restrict__ B,
              _Float16* __restrict__ Q, _Float16* __restrict__ Kh,
              _Float16* __restrict__ Vt) {
  const int bm = blockIdx.y, bn = blockIdx.x;
  const _Float16* Ab = A + (long long)bm * 128 * 1024;
  const _Float16* Bb = B + (long long)bn * 128 * 1024;

  __shared__ _Float16 As[128][64];
  __shared__ _Float16 Bs[128][64];

  const int tid = threadIdx.x;
  const int wave = tid >> 6, lane = tid & 63;
  const int quad = lane >> 4, lr = lane & 15;
  const int wm = (wave >> 1) << 6, wn = (wave & 1) << 6;
  const int srow = lane >> 3;
  const int goff = ((lane & 7) ^ srow) << 3;

  floatx4 acc[4][4] = {};
  const _Float16* ga = Ab + (long long)(wave * 8 + srow) * 1024 + goff;
  const _Float16* gb = Bb + (long long)(wave * 8 + srow) * 1024 + goff;

  for (int k0 = 0; k0 < 1024; k0 += 64) {
    __syncthreads();
#pragma unroll
    for (int c = 0; c < 4; ++c) {
      load16_lds(&As[wave * 8 + 32 * c][0], ga + c * 32 * 1024);
      load16_lds(&Bs[wave * 8 + 32 * c][0], gb + c * 32 * 1024);
    }
    ga += 64; gb += 64;
    __syncthreads();

#pragma unroll
    for (int kk = 0; kk < 2; ++kk) {
      half8 af[4], bf[4];
#pragma unroll
      for (int i = 0; i < 4; ++i) {
        const int ra = wm + (i << 4) + lr;
        const int rb = wn + (i << 4) + lr;
        af[i] = *(const half8*)&As[ra][(((kk << 2) + quad) ^ (ra & 7)) << 3];
        bf[i] = *(const half8*)&Bs[rb][(((kk << 2) + quad) ^ (rb & 7)) << 3];
      }
#pragma unroll
      for (int i = 0; i < 4; ++i)
#pragma unroll
        for (int j = 0; j < 4; ++j)
          acc[i][j] = __builtin_amdgcn_mfma_f32_16x16x32_f16(af[i], bf[j], acc[i][j], 0, 0, 0);
    }
  }

  const int colb = bn * 128 + wn + lr;
  const int rowb = bm * 128 + wm + (quad << 2);

  if (bn < 16) {
    _Float16* C = (bn < 8) ? Q : Kh;
    const int cb = colb & 1023;
#pragma unroll
    for (int i = 0; i < 4; ++i)
#pragma unroll
      for (int j = 0; j < 4; ++j)
#pragma unroll
        for (int r = 0; r < 4; ++r)
          C[(long long)(rowb + (i << 4) + r) * 1024 + cb + (j << 4)] =
              (_Float16)acc[i][j][r];
  } else {
    const int b = rowb >> 11;
    const int tb = rowb & 2047;
#pragma unroll
    for (int i = 0; i < 4; ++i) {
      const int tok = tb + (i << 4);
#pragma unroll
      for (int j = 0; j < 4; ++j) {
        const int d = (colb & 1023) + (j << 4);
        half4v v = { (_Float16)acc[i][j][0], (_Float16)acc[i][j][1],
                     (_Float16)acc[i][j][2], (_Float16)acc[i][j][3] };
        *(half4v*)&Vt[(long long)b * 2097152 + (long long)d * 2048 + tok] = v;
      }
    }
  }
}

// ---------------------------------------------------------------- S GEMM
// P_unnorm[64 q x 256 k] = exp(mask(Q K^T/32)) f16 + atomic row sums.
// R5 body; R8 XCD-pinned decode: pair p = b&15 -> (bz=p>>2, pn=p&3) covering
// K-slabs bn=pn (32-4pn q-tiles) and bn=7-pn (4+4pn q-tiles); inner = b>>4.
// All blocks of a pair land on XCD p%8 (grid stride 16 preserves b%8 == p%8),
// keeping that XCD's two K-slabs (2 x 512 KB) hot in its local L2.
__global__ __launch_bounds__(256)
void gemm_s_exp(const _Float16* __restrict__ Q, const _Float16* __restrict__ Kh,
                _Float16* __restrict__ P, float* __restrict__ l) {
  const int p = blockIdx.x & 15;
  const int inner = blockIdx.x >> 4;        // 0..35
  const int bz = p >> 2;
  const int pn = p & 3;
  const int sa = 32 - 4 * pn;
  int bn, bm;
  if (inner < sa) { bn = pn;      bm = 4 * pn + inner; }
  else            { bn = 7 - pn;  bm = 4 * (7 - pn) + (inner - sa); }

  const _Float16* Ab = Q  + (long long)bz * 2097152 + (long long)bm * 64 * 1024;
  const _Float16* Bb = Kh + (long long)bz * 2097152 + (long long)bn * 256 * 1024;
  const int nmaxl = bm * 64 + 63 - bn * 256;  // max local col needed (>=0)

  __shared__ _Float16 As[64][64];
  __shared__ _Float16 Bs[256][64];

  const int tid = threadIdx.x;
  const int wave = tid >> 6, lane = tid & 63;
  const int quad = lane >> 4, lr = lane & 15;
  const int srow = lane >> 3;
  const int goff = ((lane & 7) ^ srow) << 3;

  floatx4 acc[4][4] = {};
  const _Float16* ga = Ab + (long long)(wave * 16 + srow) * 1024 + goff;
  const _Float16* gb = Bb + (long long)(wave * 64 + srow) * 1024 + goff;

  for (int k0 = 0; k0 < 1024; k0 += 64) {
    __syncthreads();
    load16_lds(&As[wave * 16][0],     ga);
    load16_lds(&As[wave * 16 + 8][0], ga + 8 * 1024);
#pragma unroll
    for (int c = 0; c < 8; ++c)
      if (wave * 64 + 8 * c <= nmaxl)
        load16_lds(&Bs[wave * 64 + 8 * c][0], gb + c * 8 * 1024);
    ga += 64; gb += 64;
    __syncthreads();

#pragma unroll
    for (int kk = 0; kk < 2; ++kk) {
      half8 af[4], bf[4];
#pragma unroll
      for (int i = 0; i < 4; ++i) {
        const int ra = (i << 4) + lr;
        af[i] = *(const half8*)&As[ra][(((kk << 2) + quad) ^ (ra & 7)) << 3];
      }
#pragma unroll
      for (int j = 0; j < 4; ++j)
        if (wave * 64 + (j << 4) <= nmaxl) {
          const int rb = wave * 64 + (j << 4) + lr;
          bf[j] = *(const half8*)&Bs[rb][(((kk << 2) + quad) ^ (rb & 7)) << 3];
        }
#pragma unroll
      for (int i = 0; i < 4; ++i)
#pragma unroll
        for (int j = 0; j < 4; ++j)
          if (wave * 64 + (j << 4) <= nmaxl)
            acc[i][j] = __builtin_amdgcn_mfma_f32_16x16x32_f16(af[i], bf[j], acc[i][j], 0, 0, 0);
    }
  }

  const int n0 = bn * 256 + wave * 64;
  const int rowq = bm * 64 + (quad << 2);
  _Float16* Pb = P + (long long)bz * 4194304;
  const float scl = 0.03125f;

  float rs[4][4];
#pragma unroll
  for (int i = 0; i < 4; ++i)
#pragma unroll
    for (int r = 0; r < 4; ++r) rs[i][r] = 0.f;

#pragma unroll
  for (int j = 0; j < 4; ++j)
    if (wave * 64 + (j << 4) <= nmaxl) {
      const int kcol = n0 + (j << 4) + lr;
#pragma unroll
      for (int i = 0; i < 4; ++i)
#pragma unroll
        for (int r = 0; r < 4; ++r) {
          const int q = rowq + (i << 4) + r;
          const float pv = (kcol <= q) ? __expf(acc[i][j][r] * scl) : 0.f;
          Pb[(long long)q * 2048 + kcol] = (_Float16)pv;
          rs[i][r] += pv;
        }
    }

#pragma unroll
  for (int i = 0; i < 4; ++i)
#pragma unroll
    for (int r = 0; r < 4; ++r) {
#pragma unroll
      for (int off = 1; off < 16; off <<= 1)
        rs[i][r] += __shfl_xor(rs[i][r], off);
    }
  if (lr == 0) {
    float* lb = l + bz * 2048;
#pragma unroll
    for (int i = 0; i < 4; ++i)
#pragma unroll
      for (int r = 0; r < 4; ++r)
        atomicAdd(&lb[rowq + (i << 4) + r], rs[i][r]);
  }
}

// ---------------------------------------------------------------- PV GEMM
// out[64 q x 256 d] = (P_unnorm V) / l[q]; Keff = 64*(bm+1); heavy-first.
// R8 XCD-pinned decode: group g = b&15 -> (bz=g>>2, dn=g&3); inner = b>>4
// gives bm = 31-inner (heavy first). XCD g%8 keeps its two V-slabs hot.
__global__ __launch_bounds__(256)
void gemm_pv(const _Float16* __restrict__ P, const _Float16* __restrict__ Vt,
             const float* __restrict__ l, float* __restrict__ out) {
  const int g = blockIdx.x & 15;
  const int inner = blockIdx.x >> 4;   // 0..31
  const int bz = g >> 2;
  const int dn = g & 3;
  const int bm = 31 - inner;           // heavy (large Keff) first
  const int Keff = 64 * (bm + 1);

  const _Float16* Ab = P  + (long long)bz * 4194304 + (long long)bm * 64 * 2048;
  const _Float16* Bb = Vt + (long long)bz * 2097152 + (long long)dn * 256 * 2048;

  __shared__ _Float16 As[64][64];
  __shared__ _Float16 Bs[256][64];

  const int tid = threadIdx.x;
  const int wave = tid >> 6, lane = tid & 63;
  const int quad = lane >> 4, lr = lane & 15;
  const int srow = lane >> 3;
  const int goff = ((lane & 7) ^ srow) << 3;

  floatx4 acc[4][4] = {};
  const _Float16* ga = Ab + (long long)(wave * 16 + srow) * 2048 + goff;
  const _Float16* gb = Bb + (long long)(wave * 64 + srow) * 2048 + goff;

  for (int k0 = 0; k0 < Keff; k0 += 64) {
    __syncthreads();
    load16_lds(&As[wave * 16][0],     ga);
    load16_lds(&As[wave * 16 + 8][0], ga + 8 * 2048);
#pragma unroll
    for (int c = 0; c < 8; ++c)
      load16_lds(&Bs[wave * 64 + 8 * c][0], gb + c * 8 * 2048);
    ga += 64; gb += 64;
    __syncthreads();

#pragma unroll
    for (int kk = 0; kk < 2; ++kk) {
      half8 af[4], bf[4];
#pragma unroll
      for (int i = 0; i < 4; ++i) {
        const int ra = (i << 4) + lr;
        af[i] = *(const half8*)&As[ra][(((kk << 2) + quad) ^ (ra & 7)) << 3];
      }
#pragma unroll
      for (int j = 0; j < 4; ++j) {
        const int rb = wave * 64 + (j << 4) + lr;
        bf[j] = *(const half8*)&Bs[rb][(((kk << 2) + quad) ^ (rb & 7)) << 3];
      }
#pragma unroll
      for (int i = 0; i < 4; ++i)
#pragma unroll
        for (int j = 0; j < 4; ++j)
          acc[i][j] = __builtin_amdgcn_mfma_f32_16x16x32_f16(af[i], bf[j], acc[i][j], 0, 0, 0);
    }
  }

  const int d0 = dn * 256 + wave * 64;
  const int rowq = bm * 64 + (quad << 2);
  const float* lb = l + bz * 2048;
  float* Cb = out + (long long)bz * 2097152;

  float linv[4][4];
#pragma unroll
  for (int i = 0; i < 4; ++i)
#pragma unroll
    for (int r = 0; r < 4; ++r)
      linv[i][r] = 1.0f / lb[rowq + (i << 4) + r];

#pragma unroll
  for (int i = 0; i < 4; ++i)
#pragma unroll
    for (int j = 0; j < 4; ++j)
#pragma unroll
      for (int r = 0; r < 4; ++r)
        Cb[(long long)(rowq + (i << 4) + r) * 1024 + d0 + (j << 4) + lr] =
            acc[i][j][r] * linv[i][r];
}

// ---------------------------------------------------------------- launch

extern "C" void kernel_launch(void* const* d_in, const int* in_sizes, int n_in,
                              void* d_out, int out_size, void* d_ws, size_t ws_size,
                              hipStream_t stream) {
  const float* x  = (const float*)d_in[0];
  const float* Wq = (const float*)d_in[1];
  const float* Wk = (const float*)d_in[2];
  const float* Wv = (const float*)d_in[3];
  float* out = (float*)d_out;

  char* ws = (char*)d_ws;
  _Float16* xh = (_Float16*)(ws);               // 8192x1024 f16   (16 MiB)
  _Float16* Wt = (_Float16*)(ws + 16777216);    // 3072x1024 f16   ( 6 MiB)
  _Float16* Q  = (_Float16*)(ws + 23068672);    // 8192x1024 f16
  _Float16* Kh = (_Float16*)(ws + 39845888);    // 8192x1024 f16
  _Float16* Vt = (_Float16*)(ws + 56623104);    // 4x1024x2048 f16
  _Float16* P  = (_Float16*)(ws + 73400320);    // 4x2048x2048 f16 unnormalized
  float*    l  = (float*)   (ws + 106954752);   // 4x2048 fp32 row sums

  conv_f32_f16<<<8200, 256, 0, stream>>>(x, xh, l);
  transpose_w<<<dim3(32, 32, 3), dim3(32, 8), 0, stream>>>(Wq, Wk, Wv, Wt);

  // fused QKV: [8192,1024] x [3072,1024]^T
  gemm_qkv<<<dim3(24, 64), 256, 0, stream>>>(xh, Wt, Q, Kh, Vt);

  // P_unnorm = exp(mask(Q K^T / 32)) + row sums; XCD-pinned triangular grid
  gemm_s_exp<<<576, 256, 0, stream>>>(Q, Kh, P, l);

  // out = (P V) / l; XCD-pinned, heavy-first
  gemm_pv<<<512, 256, 0, stream>>>(P, Vt, l, out);
}

// Round 9
// 250.133 us; speedup vs baseline: 1.7259x; 1.0128x over previous
//
#include <hip/hip_runtime.h>

// CausalSelfAttention B=4, N=2048, D=1024, scale 1/32.
// f16 convert(+zero l) -> fused QKV GEMM (128x128, BK=64, 2-barrier) ->
// S=QK^T 128x128 tiles (fused mask+exp + atomic row sums) -> PV 128x128
// tiles (causal K-limit at 128 gran, heavy-first) / rowsum.
//
// R9 rationale: R4-R8 showed S/PV invariant (~165 us) under occupancy, dbuf,
// direct-stream, XCD pinning => bound by staging traffic per output
// (~(1/tm+1/tn) bytes/out) through the L2-miss path (~10-15 B/cyc/CU).
// Square 128x128 tiles minimize bytes/output (-20% vs 64x256) and reuse the
// proven QKV body (conflicts=0, 736 TF at large shape).

typedef __attribute__((ext_vector_type(8))) _Float16 half8;
typedef __attribute__((ext_vector_type(4))) _Float16 half4v;
typedef __attribute__((ext_vector_type(4))) float floatx4;

#define AS1 __attribute__((address_space(1)))
#define AS3 __attribute__((address_space(3)))

__device__ __forceinline__ void load16_lds(void* lds, const void* g) {
  __builtin_amdgcn_global_load_lds((AS1 void*)g, (AS3 void*)lds, 16, 0, 0);
}

// ---------------------------------------------------------------- conv + zero

__global__ __launch_bounds__(256)
void conv_f32_f16(const float* __restrict__ in, _Float16* __restrict__ out,
                  float* __restrict__ l) {
  if (blockIdx.x < 8192) {
    const int i = (blockIdx.x * 256 + threadIdx.x) << 2;
    float4 v = *(const float4*)(in + i);
    half4v o = { (_Float16)v.x, (_Float16)v.y, (_Float16)v.z, (_Float16)v.w };
    *(half4v*)(out + i) = o;
  } else {
    const int i = ((blockIdx.x - 8192) * 256 + threadIdx.x) << 2;
    *(float4*)(l + i) = float4{0.f, 0.f, 0.f, 0.f};
  }
}

// W [1024(k),1024(n)] fp32 -> Wt [n][k] f16 for 3 weights -> [3072][1024]
__global__ __launch_bounds__(256)
void transpose_w(const float* __restrict__ W0, const float* __restrict__ W1,
                 const float* __restrict__ W2, _Float16* __restrict__ Wt) {
  const float* W = blockIdx.z == 0 ? W0 : (blockIdx.z == 1 ? W1 : W2);
  _Float16* out = Wt + (long long)blockIdx.z * 1048576;
  __shared__ _Float16 t[32][33];
  const int tx = threadIdx.x, ty = threadIdx.y;
  const int n0 = blockIdx.x << 5, k0 = blockIdx.y << 5;
#pragma unroll
  for (int i = 0; i < 4; ++i)
    t[ty + i * 8][tx] = (_Float16)W[(long long)(k0 + ty + i * 8) * 1024 + n0 + tx];
  __syncthreads();
#pragma unroll
  for (int i = 0; i < 4; ++i)
    out[(long long)(n0 + ty + i * 8) * 1024 + k0 + tx] = t[tx][ty + i * 8];
}

// ---------------------------------------------------------------- QKV GEMM
// Unchanged (736 TF, conflicts 0): 128x128 tile, BK=64, 4 waves 2x2.
__global__ __launch_bounds__(256)
void gemm_qkv(const _Float16* __restrict__ A, const _Float16* __restrict__ B,
              _Float16* __restrict__ Q, _Float16* __restrict__ Kh,
              _Float16* __restrict__ Vt) {
  const int bm = blockIdx.y, bn = blockIdx.x;
  const _Float16* Ab = A + (long long)bm * 128 * 1024;
  const _Float16* Bb = B + (long long)bn * 128 * 1024;

  __shared__ _Float16 As[128][64];
  __shared__ _Float16 Bs[128][64];

  const int tid = threadIdx.x;
  const int wave = tid >> 6, lane = tid & 63;
  const int quad = lane >> 4, lr = lane & 15;
  const int wm = (wave >> 1) << 6, wn = (wave & 1) << 6;
  const int srow = lane >> 3;
  const int goff = ((lane & 7) ^ srow) << 3;

  floatx4 acc[4][4] = {};
  const _Float16* ga = Ab + (long long)(wave * 8 + srow) * 1024 + goff;
  const _Float16* gb = Bb + (long long)(wave * 8 + srow) * 1024 + goff;

  for (int k0 = 0; k0 < 1024; k0 += 64) {
    __syncthreads();
#pragma unroll
    for (int c = 0; c < 4; ++c) {
      load16_lds(&As[wave * 8 + 32 * c][0], ga + c * 32 * 1024);
      load16_lds(&Bs[wave * 8 + 32 * c][0], gb + c * 32 * 1024);
    }
    ga += 64; gb += 64;
    __syncthreads();

#pragma unroll
    for (int kk = 0; kk < 2; ++kk) {
      half8 af[4], bf[4];
#pragma unroll
      for (int i = 0; i < 4; ++i) {
        const int ra = wm + (i << 4) + lr;
        const int rb = wn + (i << 4) + lr;
        af[i] = *(const half8*)&As[ra][(((kk << 2) + quad) ^ (ra & 7)) << 3];
        bf[i] = *(const half8*)&Bs[rb][(((kk << 2) + quad) ^ (rb & 7)) << 3];
      }
#pragma unroll
      for (int i = 0; i < 4; ++i)
#pragma unroll
        for (int j = 0; j < 4; ++j)
          acc[i][j] = __builtin_amdgcn_mfma_f32_16x16x32_f16(af[i], bf[j], acc[i][j], 0, 0, 0);
    }
  }

  const int colb = bn * 128 + wn + lr;
  const int rowb = bm * 128 + wm + (quad << 2);

  if (bn < 16) {
    _Float16* C = (bn < 8) ? Q : Kh;
    const int cb = colb & 1023;
#pragma unroll
    for (int i = 0; i < 4; ++i)
#pragma unroll
      for (int j = 0; j < 4; ++j)
#pragma unroll
        for (int r = 0; r < 4; ++r)
          C[(long long)(rowb + (i << 4) + r) * 1024 + cb + (j << 4)] =
              (_Float16)acc[i][j][r];
  } else {
    const int b = rowb >> 11;
    const int tb = rowb & 2047;
#pragma unroll
    for (int i = 0; i < 4; ++i) {
      const int tok = tb + (i << 4);
#pragma unroll
      for (int j = 0; j < 4; ++j) {
        const int d = (colb & 1023) + (j << 4);
        half4v v = { (_Float16)acc[i][j][0], (_Float16)acc[i][j][1],
                     (_Float16)acc[i][j][2], (_Float16)acc[i][j][3] };
        *(half4v*)&Vt[(long long)b * 2097152 + (long long)d * 2048 + tok] = v;
      }
    }
  }
}

// ---------------------------------------------------------------- S GEMM
// P_unnorm[128 q x 128 k] = exp(mask(Q K^T/32)) f16 + atomic row sums.
// Exact QKV body; compact triangular grid bn <= bm (136 tiles/batch).
__global__ __launch_bounds__(256)
void gemm_s_exp(const _Float16* __restrict__ Q, const _Float16* __restrict__ Kh,
                _Float16* __restrict__ P, float* __restrict__ l) {
  int t = blockIdx.x;
  int bm = 0;
  for (;;) { const int c = bm + 1; if (t < c) break; t -= c; ++bm; }
  const int bn = t;
  const int bz = blockIdx.y;

  const _Float16* Ab = Q  + (long long)bz * 2097152 + (long long)bm * 128 * 1024;
  const _Float16* Bb = Kh + (long long)bz * 2097152 + (long long)bn * 128 * 1024;

  __shared__ _Float16 As[128][64];
  __shared__ _Float16 Bs[128][64];

  const int tid = threadIdx.x;
  const int wave = tid >> 6, lane = tid & 63;
  const int quad = lane >> 4, lr = lane & 15;
  const int wm = (wave >> 1) << 6, wn = (wave & 1) << 6;
  const int srow = lane >> 3;
  const int goff = ((lane & 7) ^ srow) << 3;

  floatx4 acc[4][4] = {};
  const _Float16* ga = Ab + (long long)(wave * 8 + srow) * 1024 + goff;
  const _Float16* gb = Bb + (long long)(wave * 8 + srow) * 1024 + goff;

  for (int k0 = 0; k0 < 1024; k0 += 64) {
    __syncthreads();
#pragma unroll
    for (int c = 0; c < 4; ++c) {
      load16_lds(&As[wave * 8 + 32 * c][0], ga + c * 32 * 1024);
      load16_lds(&Bs[wave * 8 + 32 * c][0], gb + c * 32 * 1024);
    }
    ga += 64; gb += 64;
    __syncthreads();

#pragma unroll
    for (int kk = 0; kk < 2; ++kk) {
      half8 af[4], bf[4];
#pragma unroll
      for (int i = 0; i < 4; ++i) {
        const int ra = wm + (i << 4) + lr;
        const int rb = wn + (i << 4) + lr;
        af[i] = *(const half8*)&As[ra][(((kk << 2) + quad) ^ (ra & 7)) << 3];
        bf[i] = *(const half8*)&Bs[rb][(((kk << 2) + quad) ^ (rb & 7)) << 3];
      }
#pragma unroll
      for (int i = 0; i < 4; ++i)
#pragma unroll
        for (int j = 0; j < 4; ++j)
          acc[i][j] = __builtin_amdgcn_mfma_f32_16x16x32_f16(af[i], bf[j], acc[i][j], 0, 0, 0);
    }
  }

  // epilogue: p = exp(s/32) masked; f16 store; row-sum -> atomicAdd l[row]
  const int colb = bn * 128 + wn + lr;
  const int rowb = bm * 128 + wm + (quad << 2);
  _Float16* Pb = P + (long long)bz * 4194304;
  const float scl = 0.03125f;

  float rs[4][4];
#pragma unroll
  for (int i = 0; i < 4; ++i)
#pragma unroll
    for (int r = 0; r < 4; ++r) rs[i][r] = 0.f;

#pragma unroll
  for (int i = 0; i < 4; ++i)
#pragma unroll
    for (int j = 0; j < 4; ++j)
#pragma unroll
      for (int r = 0; r < 4; ++r) {
        const int q = rowb + (i << 4) + r;
        const int kcol = colb + (j << 4);
        const float pv = (kcol <= q) ? __expf(acc[i][j][r] * scl) : 0.f;
        Pb[(long long)q * 2048 + kcol] = (_Float16)pv;
        rs[i][r] += pv;
      }

#pragma unroll
  for (int i = 0; i < 4; ++i)
#pragma unroll
    for (int r = 0; r < 4; ++r) {
#pragma unroll
      for (int off = 1; off < 16; off <<= 1)
        rs[i][r] += __shfl_xor(rs[i][r], off);
    }
  if (lr == 0) {
    float* lb = l + bz * 2048;
#pragma unroll
    for (int i = 0; i < 4; ++i)
#pragma unroll
      for (int r = 0; r < 4; ++r)
        atomicAdd(&lb[rowb + (i << 4) + r], rs[i][r]);
  }
}

// ---------------------------------------------------------------- PV GEMM
// out[128 q x 128 d] = (P_unnorm V) / l[q]; Keff = 128*(bm+1); heavy-first.
// Exact QKV body with lda/ldb = 2048.
__global__ __launch_bounds__(256)
void gemm_pv(const _Float16* __restrict__ P, const _Float16* __restrict__ Vt,
             const float* __restrict__ l, float* __restrict__ out) {
  const int dn = blockIdx.x;           // 0..7
  const int bm = 15 - blockIdx.y;      // heavy (large Keff) first
  const int bz = blockIdx.z;
  const int Keff = 128 * (bm + 1);

  const _Float16* Ab = P  + (long long)bz * 4194304 + (long long)bm * 128 * 2048;
  const _Float16* Bb = Vt + (long long)bz * 2097152 + (long long)dn * 128 * 2048;

  __shared__ _Float16 As[128][64];
  __shared__ _Float16 Bs[128][64];

  const int tid = threadIdx.x;
  const int wave = tid >> 6, lane = tid & 63;
  const int quad = lane >> 4, lr = lane & 15;
  const int wm = (wave >> 1) << 6, wn = (wave & 1) << 6;
  const int srow = lane >> 3;
  const int goff = ((lane & 7) ^ srow) << 3;

  floatx4 acc[4][4] = {};
  const _Float16* ga = Ab + (long long)(wave * 8 + srow) * 2048 + goff;
  const _Float16* gb = Bb + (long long)(wave * 8 + srow) * 2048 + goff;

  for (int k0 = 0; k0 < Keff; k0 += 64) {
    __syncthreads();
#pragma unroll
    for (int c = 0; c < 4; ++c) {
      load16_lds(&As[wave * 8 + 32 * c][0], ga + (long long)c * 32 * 2048);
      load16_lds(&Bs[wave * 8 + 32 * c][0], gb + (long long)c * 32 * 2048);
    }
    ga += 64; gb += 64;
    __syncthreads();

#pragma unroll
    for (int kk = 0; kk < 2; ++kk) {
      half8 af[4], bf[4];
#pragma unroll
      for (int i = 0; i < 4; ++i) {
        const int ra = wm + (i << 4) + lr;
        const int rb = wn + (i << 4) + lr;
        af[i] = *(const half8*)&As[ra][(((kk << 2) + quad) ^ (ra & 7)) << 3];
        bf[i] = *(const half8*)&Bs[rb][(((kk << 2) + quad) ^ (rb & 7)) << 3];
      }
#pragma unroll
      for (int i = 0; i < 4; ++i)
#pragma unroll
        for (int j = 0; j < 4; ++j)
          acc[i][j] = __builtin_amdgcn_mfma_f32_16x16x32_f16(af[i], bf[j], acc[i][j], 0, 0, 0);
    }
  }

  const int colb = dn * 128 + wn + lr;
  const int rowb = bm * 128 + wm + (quad << 2);
  const float* lb = l + bz * 2048;
  float* Cb = out + (long long)bz * 2097152;

  float linv[4][4];
#pragma unroll
  for (int i = 0; i < 4; ++i)
#pragma unroll
    for (int r = 0; r < 4; ++r)
      linv[i][r] = 1.0f / lb[rowb + (i << 4) + r];

#pragma unroll
  for (int i = 0; i < 4; ++i)
#pragma unroll
    for (int j = 0; j < 4; ++j)
#pragma unroll
      for (int r = 0; r < 4; ++r)
        Cb[(long long)(rowb + (i << 4) + r) * 1024 + colb + (j << 4)] =
            acc[i][j][r] * linv[i][r];
}

// ---------------------------------------------------------------- launch

extern "C" void kernel_launch(void* const* d_in, const int* in_sizes, int n_in,
                              void* d_out, int out_size, void* d_ws, size_t ws_size,
                              hipStream_t stream) {
  const float* x  = (const float*)d_in[0];
  const float* Wq = (const float*)d_in[1];
  const float* Wk = (const float*)d_in[2];
  const float* Wv = (const float*)d_in[3];
  float* out = (float*)d_out;

  char* ws = (char*)d_ws;
  _Float16* xh = (_Float16*)(ws);               // 8192x1024 f16   (16 MiB)
  _Float16* Wt = (_Float16*)(ws + 16777216);    // 3072x1024 f16   ( 6 MiB)
  _Float16* Q  = (_Float16*)(ws + 23068672);    // 8192x1024 f16
  _Float16* Kh = (_Float16*)(ws + 39845888);    // 8192x1024 f16
  _Float16* Vt = (_Float16*)(ws + 56623104);    // 4x1024x2048 f16
  _Float16* P  = (_Float16*)(ws + 73400320);    // 4x2048x2048 f16 unnormalized
  float*    l  = (float*)   (ws + 106954752);   // 4x2048 fp32 row sums

  conv_f32_f16<<<8200, 256, 0, stream>>>(x, xh, l);
  transpose_w<<<dim3(32, 32, 3), dim3(32, 8), 0, stream>>>(Wq, Wk, Wv, Wt);

  // fused QKV: [8192,1024] x [3072,1024]^T
  gemm_qkv<<<dim3(24, 64), 256, 0, stream>>>(xh, Wt, Q, Kh, Vt);

  // P_unnorm = exp(mask(Q K^T / 32)) + row sums; compact triangular grid
  gemm_s_exp<<<dim3(136, 4), 256, 0, stream>>>(Q, Kh, P, l);

  // out = (P V) / l; causal K-limit at 128 gran, heavy-first
  gemm_pv<<<dim3(8, 16, 4), 256, 0, stream>>>(P, Vt, l, out);
}